// Round 1
// 1535.471 us; speedup vs baseline: 1.2867x; 1.2867x over previous
//
#include <hip/hip_runtime.h>

#define SS 8
#define BB 32
#define TT 1024
#define DD 128
#define HH 32
#define NCHAIN (SS*BB)   // 256

// d_out layout (floats): [0,4096) mixed | [4096, 4096+S*B*T*D) all_out | then hfin [S*B*H]
// Stripes per all_out row (128 floats): [0:32) xB f32 (k_xb->k_scan), [96:128) hs f32
// (k_scan->k_out). k_out stages hs then overwrites the full row.

// ---- numpy float32 SIMD exp: rational P5/Q2 kernel (best-scoring: R12=1.5) ----
__device__ __forceinline__ float expf_np(float x) {
  if (x > 88.72283935546875f) return __builtin_inff();
  if (x < -87.3365478515625f) return 0.0f;
  const float magic = 12582912.0f;                  // 1.5 * 2^23
  const float q = fmaf(x, 1.44269504088896341f, magic) - magic;
  float r = fmaf(q, -6.93145752e-1f, x);
  r = fmaf(q, -1.42860677e-6f, r);
  float num = fmaf(r, 5.082762527590693718096e-04f, 6.757896990527504603057e-03f);
  num = fmaf(num, r, 5.114512081637298353406e-02f);
  num = fmaf(num, r, 2.473615434895520810817e-01f);
  num = fmaf(num, r, 7.257664613233124478488e-01f);
  num = fmaf(num, r, 9.999999999980870924916e-01f);
  float den = fmaf(r, 2.159509375685829852307e-02f, -2.742335390411667452936e-01f);
  den = fmaf(den, r, 1.0f);
  return ldexpf(num / den, (int)q);
}

// CR f32 exp/log1p via f64 libm (softplus scalar libm path — npy_logaddexpf)
__device__ __forceinline__ float expf_cr(float x)   { return (float)exp((double)x); }
__device__ __forceinline__ float log1pf_cr(float x) { return (float)log1p((double)x); }

// -------- 32-lane-group f32 sum reduction (k_out LN only; proven by out1) --
__device__ __forceinline__ float red32_add(float x) {
  int xi;
  xi = __builtin_amdgcn_update_dpp(0, __float_as_int(x), 0xB1, 0xF, 0xF, true);
  x += __int_as_float(xi);
  xi = __builtin_amdgcn_update_dpp(0, __float_as_int(x), 0x4E, 0xF, 0xF, true);
  x += __int_as_float(xi);
  xi = __builtin_amdgcn_update_dpp(0, __float_as_int(x), 0x141, 0xF, 0xF, true);
  x += __int_as_float(xi);
  xi = __builtin_amdgcn_update_dpp(0, __float_as_int(x), 0x140, 0xF, 0xF, true);
  x += __int_as_float(xi);
  x += __int_as_float(__builtin_amdgcn_ds_swizzle(__float_as_int(x), 0x401F));
  return x;
}

// cross-lane helpers for k_scan (single wave, 32 active lanes)
#define SWZ(x, pat) __int_as_float(__builtin_amdgcn_ds_swizzle(__float_as_int(x), (pat)))
#define DPPF(x, ctrl) __int_as_float(__builtin_amdgcn_update_dpp(0, __float_as_int(x), (ctrl), 0xF, 0xF, true))

// ================= K1: xB f32 stripes — k-sequential FMA (sgemm order) =====
__global__ __launch_bounds__(256) void k_xb(const float* __restrict__ x,
                                            const float* __restrict__ mask,
                                            const float* __restrict__ Bw,
                                            float* __restrict__ xb) { // = (float*)d_out + 4096
  __shared__ float bw_sh[HH][132];
  __shared__ float x_sh[8][132];
  const int r0 = blockIdx.x * 8;           // 8 rows, all within one chain
  const int chain = r0 >> 10;
  const int s = chain >> 5;
  const int b = chain & 31;
  const int tid = threadIdx.x;
  for (int i = tid; i < HH * DD; i += 256)
    bw_sh[i >> 7][i & 127] = Bw[s * HH * DD + i];
  const int t0 = r0 & 1023;
  for (int i = tid; i < 8 * DD; i += 256) {
    int rr = i >> 7, d = i & 127;
    size_t gidx = ((size_t)b * TT + t0 + rr) * DD + d;
    x_sh[rr][d] = x[gidx] * mask[gidx];
  }
  __syncthreads();
  const int rl = tid >> 5;
  const int j  = tid & 31;
  float a = 0.0f;                          // acc=0; k ascending; FMA each term
  for (int d = 0; d < DD; ++d)
    a = fmaf(x_sh[rl][d], bw_sh[j][d], a);
  xb[(size_t)(r0 + rl) * DD + j] = a;      // stripe: floats [0:32) of the row
}

// ================= K2: sequential scan — latency-path rewrite ==============
// All FP realizations preserved bit-for-bit vs the previous (passing) kernel:
//  - W1 matvec: acc=fmaf(w1[0],gap,0); k ascending; single-acc FMA chain.
//  - silu: a * (1/(1+expf_np(-a))).
//  - W2 dot: exact OpenBLAS sgemv_t 8-acc blocked order, realized lane-
//    parallel: lane i holds acc[i] via fmaf over u[i],u[8+i],u[16+i],u[24+i]
//    (ds_swizzle xor 8/16/24 gathers), fold acc_i+acc_{i+4} (xor4), then
//    (t0+t1)+(t2+t3) via DPP xor1/xor2. Lane 0 result broadcast via
//    readfirstlane (bit-exact; all lanes active).
//  - softplus: CR f64 exp/log1p, computed redundantly on all lanes from the
//    identical broadcast r (replaces lane-0 + LDS bc roundtrip).
//  - A_bar: adj is bit-identical across lanes (log_neg_A constant over h),
//    so per-lane expf_np(clip(adj*dt,-20,0)) == old lane-0 broadcast.
//  - h update: p1=ab*h; p2=xbt*dt; h=clip(p1+p2) — same source shape so the
//    compiler makes the same contraction choice. h replicated in registers on
//    all 32 lanes (removes the h_sh LDS roundtrip); h_own drives the hs/hfin
//    stores with the identical op sequence.
// Global loads (xb row, gap, own xbt) are prefetched one step ahead.
// No LDS storage, no __syncthreads.
__global__ __launch_bounds__(64) void k_scan(const float* __restrict__ xb,    // (float*)d_out + 4096
                                             float* __restrict__ out_f,       // (float*)d_out
                                             const float* __restrict__ delta_ts,
                                             const float* __restrict__ log_neg_A,
                                             const float* __restrict__ W1,
                                             const float* __restrict__ b1,
                                             const float* __restrict__ W2,
                                             const float* __restrict__ b2,
                                             float* __restrict__ hfin) {
  const int j = threadIdx.x;    // 0..31
  const int chain = blockIdx.x;
  const int s = chain >> 5, b = chain & 31;

  float w1f[33];
  #pragma unroll
  for (int k = 0; k < 33; ++k) w1f[k] = W1[(s * HH + j) * 33 + k];
  const float b1j = b1[s * HH + j];
  const float b2s = b2[s];
  const float adj = -expf_np(log_neg_A[s * HH + j]);  // A_diag via numpy exp
  const float w2a = W2[s * HH + j];
  const float w2b = W2[s * HH + (j ^ 8)];
  const float w2c = W2[s * HH + (j ^ 16)];
  const float w2d = W2[s * HH + (j ^ 24)];

  const float* xrow = xb + (size_t)chain * TT * DD;     // row t: xrow + t*DD, [0:32)
  const float* dts  = delta_ts + b * TT;
  float* hsp = out_f + 4096 + (size_t)chain * TT * DD + 96 + j;

  float h[HH];
  #pragma unroll
  for (int k = 0; k < HH; ++k) h[k] = 0.0f;
  float h_own = 0.0f;

  // prefetch t=0
  float4 xcur[8];
  #pragma unroll
  for (int q = 0; q < 8; ++q) xcur[q] = *(const float4*)(xrow + 4 * q);
  float gap  = dts[0];
  float xown = xrow[j];

  #pragma unroll 1
  for (int t = 0; t < TT; ++t) {
    // issue next-step loads early (wrap at t=1023; values unused)
    const int tn = (t + 1) & 1023;
    float4 xnxt[8];
    #pragma unroll
    for (int q = 0; q < 8; ++q) xnxt[q] = *(const float4*)(xrow + (size_t)tn * DD + 4 * q);
    const float gap_n  = dts[tn];
    const float xown_n = xrow[(size_t)tn * DD + j];

    // z @ W1.T: acc=0, k ascending, FMA each term (sgemm microkernel order)
    float a = fmaf(w1f[0], gap, 0.0f);
    #pragma unroll
    for (int k = 0; k < HH; ++k) a = fmaf(w1f[1 + k], h[k], a);
    a = a + b1j;                                       // bias after matmul
    // silu = x * sigmoid(x); sigmoid = 1/(1+np.exp(-x)) (numpy rational exp)
    const float sg = 1.0f / (1.0f + expf_np(-a));
    const float u = a * sg;

    // u @ W2.T: OpenBLAS 8-acc blocked order, lane-parallel realization.
    const float u8  = SWZ(u, 0x201F);                  // lane ^ 8
    const float u16 = SWZ(u, 0x401F);                  // lane ^ 16
    const float u24 = SWZ(u, 0x601F);                  // lane ^ 24
    float acc = fmaf(u,   w2a, 0.0f);
    acc = fmaf(u8,  w2b, acc);
    acc = fmaf(u16, w2c, acc);
    acc = fmaf(u24, w2d, acc);                         // lane i (i<8) == acc[i]
    const float acc4 = SWZ(acc, 0x101F);               // lane ^ 4
    const float tf   = __fadd_rn(acc, acc4);           // lane i (i<4) == t_i
    const float p01  = __fadd_rn(tf, DPPF(tf, 0xB1));  // lane0: t0+t1
    const float rs   = __fadd_rn(p01, DPPF(p01, 0x4E));// lane0: (t0+t1)+(t2+t3)
    float r = __int_as_float(__builtin_amdgcn_readfirstlane(__float_as_int(rs)));
    r = r + b2s;                                       // bias after matmul

    // softplus = np.logaddexp(r, 0): scalar libm path (CR exp/log1p),
    // computed redundantly on all lanes (identical bits).
    const float dt0 = fmaxf(r, 0.0f) + log1pf_cr(expf_cr(-fabsf(r)));
    float ad = adj * dt0;
    ad = fminf(fmaxf(ad, -20.0f), 0.0f);               // np.clip(-20, 0)
    const float ab = expf_np(ad);                      // A_bar via numpy exp

    // own-channel update (drives hs stripe + hfin) — identical op shape
    {
      const float p1 = ab * h_own;                     // mul
      const float p2 = xown * dt0;                     // mul
      float hk = p1 + p2;                              // add
      hk = fminf(fmaxf(hk, -50.0f), 50.0f);            // np.clip(-50, 50)
      h_own = hk;
    }
    hsp[(size_t)t * DD] = h_own;

    // replicated full-h update (register-only recurrence state)
    #pragma unroll
    for (int q = 0; q < 8; ++q) {
      const float4 xq = xcur[q];
      {
        const float p1 = ab * h[4 * q + 0];
        const float p2 = xq.x * dt0;
        float hk = p1 + p2;
        h[4 * q + 0] = fminf(fmaxf(hk, -50.0f), 50.0f);
      }
      {
        const float p1 = ab * h[4 * q + 1];
        const float p2 = xq.y * dt0;
        float hk = p1 + p2;
        h[4 * q + 1] = fminf(fmaxf(hk, -50.0f), 50.0f);
      }
      {
        const float p1 = ab * h[4 * q + 2];
        const float p2 = xq.z * dt0;
        float hk = p1 + p2;
        h[4 * q + 2] = fminf(fmaxf(hk, -50.0f), 50.0f);
      }
      {
        const float p1 = ab * h[4 * q + 3];
        const float p2 = xq.w * dt0;
        float hk = p1 + p2;
        h[4 * q + 3] = fminf(fmaxf(hk, -50.0f), 50.0f);
      }
    }

    // rotate prefetch buffers
    #pragma unroll
    for (int q = 0; q < 8; ++q) xcur[q] = xnxt[q];
    gap  = gap_n;
    xown = xown_n;
  }
  hfin[chain * HH + j] = h_own;
}

// ================= K3: y = LN(h@Cw.T + Dp*x*m)*g + b  →  all_outputs ======
__global__ __launch_bounds__(256) void k_out(float* __restrict__ out_f,
                                             const float* __restrict__ x,
                                             const float* __restrict__ mask,
                                             const float* __restrict__ Cw,
                                             const float* __restrict__ Dp,
                                             const float* __restrict__ ln_g,
                                             const float* __restrict__ ln_b) {
  __shared__ float cw_sh[HH][132];       // transposed: cw_sh[k][d]
  __shared__ float h_sh[2][8][32];
  float* all_out = out_f + 4096;
  const int tid = threadIdx.x;
  const int half = blockIdx.x & 1;
  const int chain = blockIdx.x >> 1;
  const int s = chain >> 5, b = chain & 31;
  for (int i = tid; i < DD * HH; i += 256) {
    int d = i >> 5, k = i & 31;
    cw_sh[k][d] = Cw[((size_t)s * DD + d) * HH + k];
  }
  const int grp = tid >> 5;
  const int l = tid & 31;
  const int d0 = l * 4;
  const float4 dp4 = *(const float4*)&Dp[s * DD + d0];
  const float4 g4  = *(const float4*)&ln_g[s * DD + d0];
  const float4 be4 = *(const float4*)&ln_b[s * DD + d0];
  __syncthreads();
  for (int it = 0; it < 64; ++it) {
    const int buf = it & 1;
    const int tbase = half * 512 + it * 8;
    {
      int rr = tid >> 5, k = tid & 31;
      h_sh[buf][rr][k] = all_out[((size_t)chain * TT + tbase + rr) * DD + 96 + k];
    }
    __syncthreads();
    const int t = tbase + grp;
    const size_t xoff = ((size_t)b * TT + t) * DD + d0;
    float4 xv = *(const float4*)&x[xoff];
    float4 mv = *(const float4*)&mask[xoff];
    float4 v;
    v.x = dp4.x * xv.x * mv.x;
    v.y = dp4.y * xv.y * mv.y;
    v.z = dp4.z * xv.z * mv.z;
    v.w = dp4.w * xv.w * mv.w;
    const float4* hv = (const float4*)&h_sh[buf][grp][0];
    #pragma unroll
    for (int q = 0; q < 8; ++q) {
      float4 hq = hv[q];
      float hc[4] = {hq.x, hq.y, hq.z, hq.w};
      #pragma unroll
      for (int c = 0; c < 4; ++c) {
        float4 cw = *(const float4*)&cw_sh[4 * q + c][d0];
        float hk = hc[c];
        v.x = fmaf(hk, cw.x, v.x);
        v.y = fmaf(hk, cw.y, v.y);
        v.z = fmaf(hk, cw.z, v.z);
        v.w = fmaf(hk, cw.w, v.w);
      }
    }
    float sum = red32_add((v.x + v.y) + (v.z + v.w));
    float mu = sum * (1.0f / 128.0f);
    float dx = v.x - mu, dy = v.y - mu, dz = v.z - mu, dw = v.w - mu;
    float ss = red32_add((dx * dx + dy * dy) + (dz * dz + dw * dw));
    float var = ss * (1.0f / 128.0f);
    float sc = rsqrtf(var + 1e-5f);
    float4 o;
    o.x = fmaf(dx * sc, g4.x, be4.x);
    o.y = fmaf(dy * sc, g4.y, be4.y);
    o.z = fmaf(dz * sc, g4.z, be4.z);
    o.w = fmaf(dw * sc, g4.w, be4.w);
    *(float4*)&all_out[((size_t)chain * TT + t) * DD + d0] = o;
  }
}

// ================= K4: g1[b][i] = silu(concat[b,:]·gW1[i,:] + gb1[i]) ======
__global__ __launch_bounds__(256) void k_g1(const float* __restrict__ all_out,
                                            const float* __restrict__ gW1,
                                            const float* __restrict__ gb1,
                                            float* __restrict__ g1) {
  const int idx = blockIdx.x * 256 + threadIdx.x;
  const int b = idx & 31, i = idx >> 5;
  const float* wrow = gW1 + (size_t)i * 1024;
  float a0 = 0.f, a1 = 0.f, a2 = 0.f, a3 = 0.f;
  for (int j4 = 0; j4 < 1024; j4 += 4) {
    float4 w = *(const float4*)&wrow[j4];
    int sI = j4 >> 7, d = j4 & 127;
    float4 c = *(const float4*)&all_out[(((size_t)(sI * 32 + b)) * TT + 1023) * DD + d];
    a0 = fmaf(w.x, c.x, a0);
    a1 = fmaf(w.y, c.y, a1);
    a2 = fmaf(w.z, c.z, a2);
    a3 = fmaf(w.w, c.w, a3);
  }
  float r = (a0 + a1) + (a2 + a3) + gb1[i];
  g1[b * 1024 + i] = r * (1.0f / (1.0f + expf(-r)));
}

// ================= K5: gates + mixed ======================================
__global__ __launch_bounds__(256) void k_gate(const float* __restrict__ g1,
                                              const float* __restrict__ gW2,
                                              const float* __restrict__ gb2,
                                              const float* __restrict__ all_out,
                                              float* __restrict__ mixed) {
  __shared__ float gates_sh[32][8];
  const int tid = threadIdx.x;
  const int b = tid & 31, s2 = tid >> 5;
  const float* grow = g1 + b * 1024;
  const float* wrow = gW2 + s2 * 1024;
  float a0 = 0.f, a1 = 0.f, a2 = 0.f, a3 = 0.f;
  for (int i = 0; i < 1024; i += 4) {
    float4 gg = *(const float4*)&grow[i];
    float4 w  = *(const float4*)&wrow[i];
    a0 = fmaf(gg.x, w.x, a0);
    a1 = fmaf(gg.y, w.y, a1);
    a2 = fmaf(gg.z, w.z, a2);
    a3 = fmaf(gg.w, w.w, a3);
  }
  float r = (a0 + a1) + (a2 + a3) + gb2[s2];
  gates_sh[b][s2] = 1.0f / (1.0f + expf(-r));
  __syncthreads();
  for (int m = tid; m < BB * DD; m += 256) {
    int bb = m >> 7, d = m & 127;
    float acc = 0.f;
    #pragma unroll
    for (int ss2 = 0; ss2 < 8; ++ss2)
      acc = fmaf(all_out[(((size_t)(ss2 * 32 + bb)) * TT + 1023) * DD + d],
                 gates_sh[bb][ss2], acc);
    mixed[m] = acc;
  }
}

// ===========================================================================
extern "C" void kernel_launch(void* const* d_in, const int* in_sizes, int n_in,
                              void* d_out, int out_size, void* d_ws, size_t ws_size,
                              hipStream_t stream) {
  const float* x         = (const float*)d_in[0];
  const float* delta_ts  = (const float*)d_in[1];
  const float* mask      = (const float*)d_in[2];
  const float* log_neg_A = (const float*)d_in[3];
  const float* Bw        = (const float*)d_in[4];
  const float* Cw        = (const float*)d_in[5];
  const float* Dp        = (const float*)d_in[6];
  const float* W1        = (const float*)d_in[7];
  const float* b1        = (const float*)d_in[8];
  const float* W2        = (const float*)d_in[9];
  const float* b2        = (const float*)d_in[10];
  const float* ln_g      = (const float*)d_in[11];
  const float* ln_b      = (const float*)d_in[12];
  const float* gW1       = (const float*)d_in[13];
  const float* gb1       = (const float*)d_in[14];
  const float* gW2       = (const float*)d_in[15];
  const float* gb2       = (const float*)d_in[16];

  float*  out_f   = (float*)d_out;
  float*  mixed   = out_f;                                    // [32,128]
  float*  all_out = out_f + 4096;                             // [8,32,1024,128]
  float*  hfin    = out_f + 4096 + (size_t)SS * BB * TT * DD; // [8,32,32]
  float*  xb      = out_f + 4096;                             // xB stripes inside all_out

  float* g1 = (float*)d_ws;                                   // [32][1024]

  k_xb  <<<NCHAIN * TT / 8, 256, 0, stream>>>(x, mask, Bw, xb);
  k_scan<<<NCHAIN, 32, 0, stream>>>(xb, out_f, delta_ts, log_neg_A, W1, b1, W2, b2, hfin);
  k_out <<<NCHAIN * 2, 256, 0, stream>>>(out_f, x, mask, Cw, Dp, ln_g, ln_b);
  k_g1  <<<BB * 1024 / 256, 256, 0, stream>>>(all_out, gW1, gb1, g1);
  k_gate<<<1, 256, 0, stream>>>(g1, gW2, gb2, all_out, mixed);
}

// Round 4
// 1389.915 us; speedup vs baseline: 1.4214x; 1.1047x over previous
//
#include <hip/hip_runtime.h>

#define SS 8
#define BB 32
#define TT 1024
#define DD 128
#define HH 32
#define NCHAIN (SS*BB)   // 256

// d_out layout (floats): [0,4096) mixed | [4096, 4096+S*B*T*D) all_out | then hfin [S*B*H]
// Stripes per all_out row (128 floats): [0:32) xB f32 (k_xb->k_scan), [96:128) hs f32
// (k_scan->k_out). k_out stages hs then overwrites the full row.

// ---- numpy float32 SIMD exp: rational P5/Q2 kernel (best-scoring: R12=1.5) ----
__device__ __forceinline__ float expf_np(float x) {
  if (x > 88.72283935546875f) return __builtin_inff();
  if (x < -87.3365478515625f) return 0.0f;
  const float magic = 12582912.0f;                  // 1.5 * 2^23
  const float q = fmaf(x, 1.44269504088896341f, magic) - magic;
  float r = fmaf(q, -6.93145752e-1f, x);
  r = fmaf(q, -1.42860677e-6f, r);
  float num = fmaf(r, 5.082762527590693718096e-04f, 6.757896990527504603057e-03f);
  num = fmaf(num, r, 5.114512081637298353406e-02f);
  num = fmaf(num, r, 2.473615434895520810817e-01f);
  num = fmaf(num, r, 7.257664613233124478488e-01f);
  num = fmaf(num, r, 9.999999999980870924916e-01f);
  float den = fmaf(r, 2.159509375685829852307e-02f, -2.742335390411667452936e-01f);
  den = fmaf(den, r, 1.0f);
  return ldexpf(num / den, (int)q);
}

// CR f32 exp/log1p via f64 libm (softplus scalar libm path — npy_logaddexpf)
__device__ __forceinline__ float expf_cr(float x)   { return (float)exp((double)x); }
__device__ __forceinline__ float log1pf_cr(float x) { return (float)log1p((double)x); }

// -------- 32-lane-group f32 sum reduction (k_out LN only; proven by out1) --
__device__ __forceinline__ float red32_add(float x) {
  int xi;
  xi = __builtin_amdgcn_update_dpp(0, __float_as_int(x), 0xB1, 0xF, 0xF, true);
  x += __int_as_float(xi);
  xi = __builtin_amdgcn_update_dpp(0, __float_as_int(x), 0x4E, 0xF, 0xF, true);
  x += __int_as_float(xi);
  xi = __builtin_amdgcn_update_dpp(0, __float_as_int(x), 0x141, 0xF, 0xF, true);
  x += __int_as_float(xi);
  xi = __builtin_amdgcn_update_dpp(0, __float_as_int(x), 0x140, 0xF, 0xF, true);
  x += __int_as_float(xi);
  x += __int_as_float(__builtin_amdgcn_ds_swizzle(__float_as_int(x), 0x401F));
  return x;
}

// cross-lane helpers for k_scan (single wave, 32 active lanes)
#define SWZ(x, pat) __int_as_float(__builtin_amdgcn_ds_swizzle(__float_as_int(x), (pat)))
#define DPPF(x, ctrl) __int_as_float(__builtin_amdgcn_update_dpp(0, __float_as_int(x), (ctrl), 0xF, 0xF, true))

// ================= K1: xB f32 stripes — k-sequential FMA (sgemm order) =====
__global__ __launch_bounds__(256) void k_xb(const float* __restrict__ x,
                                            const float* __restrict__ mask,
                                            const float* __restrict__ Bw,
                                            float* __restrict__ xb) { // = (float*)d_out + 4096
  __shared__ float bw_sh[HH][132];
  __shared__ float x_sh[8][132];
  const int r0 = blockIdx.x * 8;           // 8 rows, all within one chain
  const int chain = r0 >> 10;
  const int s = chain >> 5;
  const int b = chain & 31;
  const int tid = threadIdx.x;
  for (int i = tid; i < HH * DD; i += 256)
    bw_sh[i >> 7][i & 127] = Bw[s * HH * DD + i];
  const int t0 = r0 & 1023;
  for (int i = tid; i < 8 * DD; i += 256) {
    int rr = i >> 7, d = i & 127;
    size_t gidx = ((size_t)b * TT + t0 + rr) * DD + d;
    x_sh[rr][d] = x[gidx] * mask[gidx];
  }
  __syncthreads();
  const int rl = tid >> 5;
  const int j  = tid & 31;
  float a = 0.0f;                          // acc=0; k ascending; FMA each term
  for (int d = 0; d < DD; ++d)
    a = fmaf(x_sh[rl][d], bw_sh[j][d], a);
  xb[(size_t)(r0 + rl) * DD + j] = a;      // stripe: floats [0:32) of the row
}

// ================= K2: sequential scan — readlane h-broadcast ==============
// Structure: each lane owns ONE h channel (h_own). The W1 matvec reads h[k]
// via v_readlane broadcast of lane k's h_own — removes the 32-channel
// replicated h update (160 VALU instrs/step) and the full-row xb prefetch
// (10 global loads/step -> 2).
// FP realizations:
//  - W1 matvec: acc=fmaf(w1f[0],gap,0); k ascending; single-acc FMA chain
//    (h_k bits identical, sourced via readlane). Unchanged vs R1-passing.
//  - silu / W2 dot (OpenBLAS 8-acc blocked order via the R1-proven swizzle
//    sequence 0x201F/0x401F/0x601F/0x101F + DPP 0xB1/0x4E + readfirstlane) /
//    CR softplus / expf_np A_bar: byte-for-byte the R1-passing forms.
//  - h update: explicit np-exact realization — __fmul_rn(ab,h),
//    __fmul_rn(xown,dt0), __fadd_rn, then clip (numpy: mul, mul, add ufuncs).
//    No fp-contract ambiguity.
__global__ __launch_bounds__(64) void k_scan(const float* __restrict__ xb,    // (float*)d_out + 4096
                                             float* __restrict__ out_f,       // (float*)d_out
                                             const float* __restrict__ delta_ts,
                                             const float* __restrict__ log_neg_A,
                                             const float* __restrict__ W1,
                                             const float* __restrict__ b1,
                                             const float* __restrict__ W2,
                                             const float* __restrict__ b2,
                                             float* __restrict__ hfin) {
  const int j = threadIdx.x;    // 0..31
  const int chain = blockIdx.x;
  const int s = chain >> 5, b = chain & 31;

  float w1f[33];
  #pragma unroll
  for (int k = 0; k < 33; ++k) w1f[k] = W1[(s * HH + j) * 33 + k];
  const float b1j = b1[s * HH + j];
  const float b2s = b2[s];
  const float adj = -expf_np(log_neg_A[s * HH + j]);  // A_diag via numpy exp
  const float w2a = W2[s * HH + j];
  const float w2b = W2[s * HH + (j ^ 8)];
  const float w2c = W2[s * HH + (j ^ 16)];
  const float w2d = W2[s * HH + (j ^ 24)];

  const float* xrow = xb + (size_t)chain * TT * DD;     // row t: xrow + t*DD, [0:32)
  const float* dts  = delta_ts + b * TT;
  float* hsp = out_f + 4096 + (size_t)chain * TT * DD + 96 + j;

  float h_own = 0.0f;

  // prefetch t=0
  float gap  = dts[0];
  float xown = xrow[j];

  #pragma unroll 1
  for (int t = 0; t < TT; ++t) {
    // issue next-step loads early (wrap at t=1023; values unused)
    const int tn = (t + 1) & 1023;
    const float gap_n  = dts[tn];
    const float xown_n = xrow[(size_t)tn * DD + j];

    // z @ W1.T: acc=0, k ascending, FMA each term (sgemm microkernel order).
    // h[k] broadcast from lane k's h_own via readlane (bit-identical values).
    float a = fmaf(w1f[0], gap, 0.0f);
    #pragma unroll
    for (int k = 0; k < HH; ++k) {
      const float hk = __int_as_float(
          __builtin_amdgcn_readlane(__float_as_int(h_own), k));
      a = fmaf(w1f[1 + k], hk, a);
    }
    a = a + b1j;                                       // bias after matmul
    // silu = x * sigmoid(x); sigmoid = 1/(1+np.exp(-x)) (numpy rational exp)
    const float sg = 1.0f / (1.0f + expf_np(-a));
    const float u = a * sg;

    // u @ W2.T: OpenBLAS 8-acc blocked order, lane-parallel realization
    // (exact R1-proven swizzle/DPP sequence).
    const float u8  = SWZ(u, 0x201F);                  // lane ^ 8
    const float u16 = SWZ(u, 0x401F);                  // lane ^ 16
    const float u24 = SWZ(u, 0x601F);                  // lane ^ 24
    float acc = fmaf(u,   w2a, 0.0f);
    acc = fmaf(u8,  w2b, acc);
    acc = fmaf(u16, w2c, acc);
    acc = fmaf(u24, w2d, acc);                         // lane i (i<8) == acc[i]
    const float acc4 = SWZ(acc, 0x101F);               // lane ^ 4
    const float tf   = __fadd_rn(acc, acc4);           // lane i (i<4) == t_i
    const float p01  = __fadd_rn(tf, DPPF(tf, 0xB1));  // lane0: t0+t1
    const float rs   = __fadd_rn(p01, DPPF(p01, 0x4E));// lane0: (t0+t1)+(t2+t3)
    float r = __int_as_float(__builtin_amdgcn_readfirstlane(__float_as_int(rs)));
    r = r + b2s;                                       // bias after matmul

    // softplus = np.logaddexp(r, 0): scalar libm path (CR exp/log1p),
    // computed redundantly on all lanes (identical bits).
    const float dt0 = fmaxf(r, 0.0f) + log1pf_cr(expf_cr(-fabsf(r)));
    float ad = adj * dt0;
    ad = fminf(fmaxf(ad, -20.0f), 0.0f);               // np.clip(-20, 0)
    const float ab = expf_np(ad);                      // A_bar via numpy exp

    // own-channel update — explicit numpy realization: mul, mul, add, clip
    {
      const float p1 = __fmul_rn(ab, h_own);           // A_bar * h
      const float p2 = __fmul_rn(xown, dt0);           // xB * dt
      float hk2 = __fadd_rn(p1, p2);                   // add
      hk2 = fminf(fmaxf(hk2, -50.0f), 50.0f);          // np.clip(-50, 50)
      h_own = hk2;
    }
    hsp[(size_t)t * DD] = h_own;

    gap  = gap_n;
    xown = xown_n;
  }
  hfin[chain * HH + j] = h_own;
}

// ================= K3: y = LN(h@Cw.T + Dp*x*m)*g + b  →  all_outputs ======
__global__ __launch_bounds__(256) void k_out(float* __restrict__ out_f,
                                             const float* __restrict__ x,
                                             const float* __restrict__ mask,
                                             const float* __restrict__ Cw,
                                             const float* __restrict__ Dp,
                                             const float* __restrict__ ln_g,
                                             const float* __restrict__ ln_b) {
  __shared__ float cw_sh[HH][132];       // transposed: cw_sh[k][d]
  __shared__ float h_sh[2][8][32];
  float* all_out = out_f + 4096;
  const int tid = threadIdx.x;
  const int half = blockIdx.x & 1;
  const int chain = blockIdx.x >> 1;
  const int s = chain >> 5, b = chain & 31;
  for (int i = tid; i < DD * HH; i += 256) {
    int d = i >> 5, k = i & 31;
    cw_sh[k][d] = Cw[((size_t)s * DD + d) * HH + k];
  }
  const int grp = tid >> 5;
  const int l = tid & 31;
  const int d0 = l * 4;
  const float4 dp4 = *(const float4*)&Dp[s * DD + d0];
  const float4 g4  = *(const float4*)&ln_g[s * DD + d0];
  const float4 be4 = *(const float4*)&ln_b[s * DD + d0];
  __syncthreads();
  for (int it = 0; it < 64; ++it) {
    const int buf = it & 1;
    const int tbase = half * 512 + it * 8;
    {
      int rr = tid >> 5, k = tid & 31;
      h_sh[buf][rr][k] = all_out[((size_t)chain * TT + tbase + rr) * DD + 96 + k];
    }
    __syncthreads();
    const int t = tbase + grp;
    const size_t xoff = ((size_t)b * TT + t) * DD + d0;
    float4 xv = *(const float4*)&x[xoff];
    float4 mv = *(const float4*)&mask[xoff];
    float4 v;
    v.x = dp4.x * xv.x * mv.x;
    v.y = dp4.y * xv.y * mv.y;
    v.z = dp4.z * xv.z * mv.z;
    v.w = dp4.w * xv.w * mv.w;
    const float4* hv = (const float4*)&h_sh[buf][grp][0];
    #pragma unroll
    for (int q = 0; q < 8; ++q) {
      float4 hq = hv[q];
      float hc[4] = {hq.x, hq.y, hq.z, hq.w};
      #pragma unroll
      for (int c = 0; c < 4; ++c) {
        float4 cw = *(const float4*)&cw_sh[4 * q + c][d0];
        float hk = hc[c];
        v.x = fmaf(hk, cw.x, v.x);
        v.y = fmaf(hk, cw.y, v.y);
        v.z = fmaf(hk, cw.z, v.z);
        v.w = fmaf(hk, cw.w, v.w);
      }
    }
    float sum = red32_add((v.x + v.y) + (v.z + v.w));
    float mu = sum * (1.0f / 128.0f);
    float dx = v.x - mu, dy = v.y - mu, dz = v.z - mu, dw = v.w - mu;
    float ss = red32_add((dx * dx + dy * dy) + (dz * dz + dw * dw));
    float var = ss * (1.0f / 128.0f);
    float sc = rsqrtf(var + 1e-5f);
    float4 o;
    o.x = fmaf(dx * sc, g4.x, be4.x);
    o.y = fmaf(dy * sc, g4.y, be4.y);
    o.z = fmaf(dz * sc, g4.z, be4.z);
    o.w = fmaf(dw * sc, g4.w, be4.w);
    *(float4*)&all_out[((size_t)chain * TT + t) * DD + d0] = o;
  }
}

// ================= K4: g1[b][i] = silu(concat[b,:]·gW1[i,:] + gb1[i]) ======
__global__ __launch_bounds__(256) void k_g1(const float* __restrict__ all_out,
                                            const float* __restrict__ gW1,
                                            const float* __restrict__ gb1,
                                            float* __restrict__ g1) {
  const int idx = blockIdx.x * 256 + threadIdx.x;
  const int b = idx & 31, i = idx >> 5;
  const float* wrow = gW1 + (size_t)i * 1024;
  float a0 = 0.f, a1 = 0.f, a2 = 0.f, a3 = 0.f;
  for (int j4 = 0; j4 < 1024; j4 += 4) {
    float4 w = *(const float4*)&wrow[j4];
    int sI = j4 >> 7, d = j4 & 127;
    float4 c = *(const float4*)&all_out[(((size_t)(sI * 32 + b)) * TT + 1023) * DD + d];
    a0 = fmaf(w.x, c.x, a0);
    a1 = fmaf(w.y, c.y, a1);
    a2 = fmaf(w.z, c.z, a2);
    a3 = fmaf(w.w, c.w, a3);
  }
  float r = (a0 + a1) + (a2 + a3) + gb1[i];
  g1[b * 1024 + i] = r * (1.0f / (1.0f + expf(-r)));
}

// ================= K5: gates + mixed ======================================
__global__ __launch_bounds__(256) void k_gate(const float* __restrict__ g1,
                                              const float* __restrict__ gW2,
                                              const float* __restrict__ gb2,
                                              const float* __restrict__ all_out,
                                              float* __restrict__ mixed) {
  __shared__ float gates_sh[32][8];
  const int tid = threadIdx.x;
  const int b = tid & 31, s2 = tid >> 5;
  const float* grow = g1 + b * 1024;
  const float* wrow = gW2 + s2 * 1024;
  float a0 = 0.f, a1 = 0.f, a2 = 0.f, a3 = 0.f;
  for (int i = 0; i < 1024; i += 4) {
    float4 gg = *(const float4*)&grow[i];
    float4 w  = *(const float4*)&wrow[i];
    a0 = fmaf(gg.x, w.x, a0);
    a1 = fmaf(gg.y, w.y, a1);
    a2 = fmaf(gg.z, w.z, a2);
    a3 = fmaf(gg.w, w.w, a3);
  }
  float r = (a0 + a1) + (a2 + a3) + gb2[s2];
  gates_sh[b][s2] = 1.0f / (1.0f + expf(-r));
  __syncthreads();
  for (int m = tid; m < BB * DD; m += 256) {
    int bb = m >> 7, d = m & 127;
    float acc = 0.f;
    #pragma unroll
    for (int ss2 = 0; ss2 < 8; ++ss2)
      acc = fmaf(all_out[(((size_t)(ss2 * 32 + bb)) * TT + 1023) * DD + d],
                 gates_sh[bb][ss2], acc);
    mixed[m] = acc;
  }
}

// ===========================================================================
extern "C" void kernel_launch(void* const* d_in, const int* in_sizes, int n_in,
                              void* d_out, int out_size, void* d_ws, size_t ws_size,
                              hipStream_t stream) {
  const float* x         = (const float*)d_in[0];
  const float* delta_ts  = (const float*)d_in[1];
  const float* mask      = (const float*)d_in[2];
  const float* log_neg_A = (const float*)d_in[3];
  const float* Bw        = (const float*)d_in[4];
  const float* Cw        = (const float*)d_in[5];
  const float* Dp        = (const float*)d_in[6];
  const float* W1        = (const float*)d_in[7];
  const float* b1        = (const float*)d_in[8];
  const float* W2        = (const float*)d_in[9];
  const float* b2        = (const float*)d_in[10];
  const float* ln_g      = (const float*)d_in[11];
  const float* ln_b      = (const float*)d_in[12];
  const float* gW1       = (const float*)d_in[13];
  const float* gb1       = (const float*)d_in[14];
  const float* gW2       = (const float*)d_in[15];
  const float* gb2       = (const float*)d_in[16];

  float*  out_f   = (float*)d_out;
  float*  mixed   = out_f;                                    // [32,128]
  float*  all_out = out_f + 4096;                             // [8,32,1024,128]
  float*  hfin    = out_f + 4096 + (size_t)SS * BB * TT * DD; // [8,32,32]
  float*  xb      = out_f + 4096;                             // xB stripes inside all_out

  float* g1 = (float*)d_ws;                                   // [32][1024]

  k_xb  <<<NCHAIN * TT / 8, 256, 0, stream>>>(x, mask, Bw, xb);
  k_scan<<<NCHAIN, 32, 0, stream>>>(xb, out_f, delta_ts, log_neg_A, W1, b1, W2, b2, hfin);
  k_out <<<NCHAIN * 2, 256, 0, stream>>>(out_f, x, mask, Cw, Dp, ln_g, ln_b);
  k_g1  <<<BB * 1024 / 256, 256, 0, stream>>>(all_out, gW1, gb1, g1);
  k_gate<<<1, 256, 0, stream>>>(g1, gW2, gb2, all_out, mixed);
}